// Round 10
// baseline (115.975 us; speedup 1.0000x reference)
//
#include <hip/hip_runtime.h>
#include <hip/hip_bf16.h>

#define NB 256      // batch == queries == classes
#define NL 256      // clips
#define SCALE 100.0f  // 1/TAU

typedef __attribute__((ext_vector_type(4))) unsigned int u32x4;
typedef __attribute__((ext_vector_type(4))) int i32x4;
typedef __attribute__((ext_vector_type(8))) __bf16 bfrag8;
typedef __attribute__((ext_vector_type(4))) float f32x4;

static __device__ __forceinline__ unsigned int pack2bf(float a, float b) {
  union { float f; unsigned int u; } ua, ub;
  ua.f = a; ub.f = b;
  unsigned int ra = (ua.u + 0x7FFFu + ((ua.u >> 16) & 1u)) >> 16;
  unsigned int rb = (ub.u + 0x7FFFu + ((ub.u >> 16) & 1u)) & 0xFFFF0000u;
  return ra | rb;
}

// ---------------------------------------------------------------------------
// Kernel 1 (round-10: SMALL BLOCKS).  Rounds 4-9's exp_t was pinned at
// ~60-67us, invariant to data source (cold 2TB/s == L3-warm 1TB/s) -> latency
// /barrier-coupling bound: 16-wave blocks, 2/CU, 8 block-wide barriers.
// Now: 256-thread blocks on 64i x 64l tiles, 2048 blocks, 9KB LDS ->
// 8 blocks/CU = 32 waves/CU, barriers couple only 4 waves.
//   dst[b][i][l] = bf16( exp(src[b,l,i]) * (is_t ? mask[i,l] : 1) )
//   sums[b][i]   = sum_l exp(src[b,l,i])   (unmasked, f32; block-local)
// ---------------------------------------------------------------------------
__global__ __launch_bounds__(256, 8) void exp_t(
    const float* __restrict__ x, const float* __restrict__ tgt,
    unsigned int* __restrict__ xsT, unsigned int* __restrict__ tsT,
    const int* __restrict__ mask,
    float* __restrict__ sumx, float* __restrict__ sumt)
{
  const int b = blockIdx.x;
  const bool is_t = (blockIdx.y != 0);
  const int itile = blockIdx.z;
  const int tid = threadIdx.x;
  const int il = tid & 63;          // i within tile
  const int h  = tid >> 6;          // l-sixteenth group (wave index)
  const int i  = itile * 64 + il;   // absolute query index
  const float* src = (is_t ? tgt : x) + (size_t)b * (NL * NB) + i;
  unsigned int* dstb = (is_t ? tsT : xsT);  // u32 units, layout [b][i][l/2]

  __shared__ __align__(16) unsigned char stg[64 * 128];  // [64 i][64 l] bf16, swizzled
  __shared__ float s_sum[4][64];

  const int r0 = tid >> 3;  // reader rows r0, r0+32  (0..31)
  const int c  = tid & 7;   // reader 16B chunk

  float tsum = 0.f;

  for (int lc = 0; lc < 4; ++lc) {
    float v[16];
    #pragma unroll
    for (int k = 0; k < 16; ++k)
      v[k] = __expf(src[(size_t)(lc * 64 + h * 16 + k) * NB]);
    #pragma unroll
    for (int k = 0; k < 16; ++k) tsum += v[k];       // denominator: pre-mask
    if (is_t) {
      const i32x4* mrow = reinterpret_cast<const i32x4*>(mask + i * NL + lc * 64 + h * 16);
      #pragma unroll
      for (int mq = 0; mq < 4; ++mq) {
        i32x4 m = mrow[mq];
        if (m.x <= 0) v[mq * 4 + 0] = 0.f;
        if (m.y <= 0) v[mq * 4 + 1] = 0.f;
        if (m.z <= 0) v[mq * 4 + 2] = 0.f;
        if (m.w <= 0) v[mq * 4 + 3] = 0.f;
      }
    }
    u32x4 p0, p1;
    p0.x = pack2bf(v[0], v[1]);   p0.y = pack2bf(v[2], v[3]);
    p0.z = pack2bf(v[4], v[5]);   p0.w = pack2bf(v[6], v[7]);
    p1.x = pack2bf(v[8], v[9]);   p1.y = pack2bf(v[10], v[11]);
    p1.z = pack2bf(v[12], v[13]); p1.w = pack2bf(v[14], v[15]);
    *reinterpret_cast<u32x4*>(&stg[il * 128 + (((h * 2 + 0) ^ (il & 7)) << 4)]) = p0;
    *reinterpret_cast<u32x4*>(&stg[il * 128 + (((h * 2 + 1) ^ (il & 7)) << 4)]) = p1;
    __syncthreads();
    u32x4 q0 = *reinterpret_cast<const u32x4*>(&stg[r0 * 128 + ((c ^ (r0 & 7)) << 4)]);
    u32x4 q1 = *reinterpret_cast<const u32x4*>(&stg[(r0 + 32) * 128 + ((c ^ (r0 & 7)) << 4)]);
    *reinterpret_cast<u32x4*>(
        dstb + ((size_t)b * 256 + itile * 64 + r0) * 128 + lc * 32 + c * 4) = q0;
    *reinterpret_cast<u32x4*>(
        dstb + ((size_t)b * 256 + itile * 64 + r0 + 32) * 128 + lc * 32 + c * 4) = q1;
    __syncthreads();
  }

  s_sum[h][il] = tsum;
  __syncthreads();
  if (h == 0) {
    float* so = is_t ? sumt : sumx;
    so[(size_t)b * 256 + i] = s_sum[0][il] + s_sum[1][il] + s_sum[2][il] + s_sum[3][il];
  }
}

// ---------------------------------------------------------------------------
// Kernel 2 (unchanged round-9 LEAN gemm — ~13us measured-by-subtraction).
//   raw[j,c]   = sum_l ex[j,l] * etm[c,l]          (mask pre-applied in et)
//   logits     = SCALE * raw * irx[j] * ict[c]     (rcp's staged in LDS)
// then log-softmax over c + label-weighted diag pick -> atomicAdd.
// XCD remap (FETCH 33MB), [b][i][l] ws reads, rule #20 static acc indexing.
// ---------------------------------------------------------------------------
__global__ __launch_bounds__(256, 2) void gemm_lse(
    const unsigned short* __restrict__ xsT,
    const unsigned short* __restrict__ tsT,
    const float* __restrict__ sumx,
    const float* __restrict__ sumt,
    const int* __restrict__ label_mat,
    float* __restrict__ out)
{
  const int n  = blockIdx.x;
  const int g  = n & 7;
  const int q  = n >> 3;
  const int i  = ((q >> 2) << 3) + g;
  const int jt = q & 3;
  const int t  = threadIdx.x;
  const int w  = t >> 6;
  const int lane = t & 63;

  __shared__ __align__(16) unsigned char As[64 * 128];    // [64 j][64 l] bf16, swizzled
  __shared__ __align__(16) unsigned char Bs[256 * 128];   // [256 c][64 l] bf16, swizzled
  __shared__ float s_irx[64];    // SCALE * rcp(sumx[j][i])
  __shared__ float s_ict[256];   //         rcp(sumt[c][i])
  __shared__ float s_rmax[4][64];
  __shared__ float s_rsum[4][64];
  __shared__ float s_diag[64];

  const int srow = t >> 3;
  const int sch  = t & 7;

  s_ict[t] = __builtin_amdgcn_rcpf(sumt[(size_t)t * 256 + i]);
  if (t < 64)
    s_irx[t] = SCALE * __builtin_amdgcn_rcpf(sumx[(size_t)(jt * 64 + t) * 256 + i]);

  f32x4 acc[4][4];
  #pragma unroll
  for (int a = 0; a < 4; ++a)
    #pragma unroll
    for (int cc = 0; cc < 4; ++cc) acc[a][cc] = f32x4{0.f, 0.f, 0.f, 0.f};

  u32x4 areg[2], breg[8];

  auto load_chunk = [&](int kc) {
    const int kofs = kc * 64;
    #pragma unroll
    for (int r = 0; r < 2; ++r) {
      int row = srow + r * 32;
      areg[r] = *reinterpret_cast<const u32x4*>(
          xsT + ((size_t)(jt * 64 + row) * 256 + i) * 256 + kofs + sch * 8);
    }
    #pragma unroll
    for (int r = 0; r < 8; ++r) {
      int row = srow + r * 32;
      breg[r] = *reinterpret_cast<const u32x4*>(
          tsT + ((size_t)row * 256 + i) * 256 + kofs + sch * 8);
    }
  };
  auto store_chunk = [&]() {
    #pragma unroll
    for (int r = 0; r < 2; ++r) {
      int row = srow + r * 32;
      *reinterpret_cast<u32x4*>(&As[row * 128 + ((sch ^ (row & 7)) << 4)]) = areg[r];
    }
    #pragma unroll
    for (int r = 0; r < 8; ++r) {
      int row = srow + r * 32;
      *reinterpret_cast<u32x4*>(&Bs[row * 128 + ((sch ^ (row & 7)) << 4)]) = breg[r];
    }
  };

  load_chunk(0);
  #pragma unroll
  for (int kc = 0; kc < 4; ++kc) {
    store_chunk();
    __syncthreads();
    if (kc < 3) load_chunk(kc + 1);
    #pragma unroll
    for (int kk = 0; kk < 2; ++kk) {
      const int co = kk * 4 + (lane >> 4);
      bfrag8 af[4], bfr[4];
      #pragma unroll
      for (int jf = 0; jf < 4; ++jf) {
        int row = jf * 16 + (lane & 15);
        af[jf] = *reinterpret_cast<const bfrag8*>(
            &As[row * 128 + ((co ^ (row & 7)) << 4)]);
      }
      #pragma unroll
      for (int cf = 0; cf < 4; ++cf) {
        int row = w * 64 + cf * 16 + (lane & 15);
        bfr[cf] = *reinterpret_cast<const bfrag8*>(
            &Bs[row * 128 + ((co ^ (row & 7)) << 4)]);
      }
      #pragma unroll
      for (int jf = 0; jf < 4; ++jf)
        #pragma unroll
        for (int cf = 0; cf < 4; ++cf)
          acc[jf][cf] = __builtin_amdgcn_mfma_f32_16x16x32_bf16(
              af[jf], bfr[cf], acc[jf][cf], 0, 0, 0);
    }
    __syncthreads();
  }

  // ---- epilogue: logits = s_irx[row] * s_ict[col] * raw ----
  const int rg = (lane >> 4) << 2;

  float fr[4][4], fc[4];
  #pragma unroll
  for (int jf = 0; jf < 4; ++jf)
    #pragma unroll
    for (int reg = 0; reg < 4; ++reg)
      fr[jf][reg] = s_irx[jf * 16 + rg + reg];
  #pragma unroll
  for (int cf = 0; cf < 4; ++cf)
    fc[cf] = s_ict[w * 64 + cf * 16 + (lane & 15)];
  #pragma unroll
  for (int jf = 0; jf < 4; ++jf)
    #pragma unroll
    for (int cf = 0; cf < 4; ++cf)
      #pragma unroll
      for (int reg = 0; reg < 4; ++reg)
        acc[jf][cf][reg] *= fr[jf][reg] * fc[cf];

  #pragma unroll
  for (int jf = 0; jf < 4; ++jf) {
    #pragma unroll
    for (int reg = 0; reg < 4; ++reg) {
      float m = fmaxf(fmaxf(acc[jf][0][reg], acc[jf][1][reg]),
                      fmaxf(acc[jf][2][reg], acc[jf][3][reg]));
      #pragma unroll
      for (int off = 1; off < 16; off <<= 1) m = fmaxf(m, __shfl_xor(m, off, 64));
      if ((lane & 15) == 0) s_rmax[w][jf * 16 + rg + reg] = m;
    }
  }
  if (w == (i >> 6) && (lane & 15) == (i & 15)) {
    const int cfd = (i >> 4) & 3;
    #pragma unroll
    for (int jf = 0; jf < 4; ++jf) {
      #pragma unroll
      for (int reg = 0; reg < 4; ++reg) {
        float v = acc[jf][0][reg];
        #pragma unroll
        for (int cf = 1; cf < 4; ++cf)
          v = (cfd == cf) ? acc[jf][cf][reg] : v;
        s_diag[jf * 16 + rg + reg] = v;
      }
    }
  }
  __syncthreads();

  #pragma unroll
  for (int jf = 0; jf < 4; ++jf) {
    #pragma unroll
    for (int reg = 0; reg < 4; ++reg) {
      int row = jf * 16 + rg + reg;
      float gm = fmaxf(fmaxf(s_rmax[0][row], s_rmax[1][row]),
                       fmaxf(s_rmax[2][row], s_rmax[3][row]));
      float sE = 0.f;
      #pragma unroll
      for (int cf = 0; cf < 4; ++cf) sE += __expf(acc[jf][cf][reg] - gm);
      #pragma unroll
      for (int off = 1; off < 16; off <<= 1) sE += __shfl_xor(sE, off, 64);
      if ((lane & 15) == 0) s_rsum[w][row] = sE;
    }
  }
  __syncthreads();

  float contrib = 0.f;
  if (t < 64) {
    const int row = t;
    float gm = fmaxf(fmaxf(s_rmax[0][row], s_rmax[1][row]),
                     fmaxf(s_rmax[2][row], s_rmax[3][row]));
    float tot = s_rsum[0][row] + s_rsum[1][row] + s_rsum[2][row] + s_rsum[3][row];
    float lse = __logf(tot) + gm;
    float lbl = (float)label_mat[i * NB + jt * 64 + row];
    contrib = lbl * (s_diag[row] - lse);
  }
  #pragma unroll
  for (int off = 32; off >= 1; off >>= 1) contrib += __shfl_down(contrib, off, 64);
  if (t == 0) atomicAdd(out, contrib * (-1.0f / 256.0f));
}

extern "C" void kernel_launch(void* const* d_in, const int* in_sizes, int n_in,
                              void* d_out, int out_size, void* d_ws, size_t ws_size,
                              hipStream_t stream) {
  const float* x   = (const float*)d_in[0];
  const float* tgt = (const float*)d_in[1];
  const int* mask  = (const int*)d_in[2];
  // d_in[3] = query_labels (unused by the reference computation)
  const int* label_mat = (const int*)d_in[4];
  float* out = (float*)d_out;

  unsigned int* xsT = (unsigned int*)d_ws;                       // 32 MiB bf16 [b][i][l]
  unsigned int* tsT = xsT + (size_t)NB * NB * NL / 2;            // 32 MiB bf16 [b][i][l]
  float* sumx = (float*)(tsT + (size_t)NB * NB * NL / 2);        // 256 KiB f32 [b][i]
  float* sumt = sumx + (size_t)NB * NB;                          // 256 KiB f32 [b][i]

  hipMemsetAsync(out, 0, sizeof(float), stream);
  exp_t<<<dim3(NB, 2, 4), 256, 0, stream>>>(x, tgt, xsT, tsT, mask, sumx, sumt);
  gemm_lse<<<dim3(1024), 256, 0, stream>>>((const unsigned short*)xsT,
                                           (const unsigned short*)tsT,
                                           sumx, sumt, label_mat, out);
}

// Round 11
// 85.211 us; speedup vs baseline: 1.3610x; 1.3610x over previous
//
#include <hip/hip_runtime.h>
#include <hip/hip_bf16.h>

#define NB 256      // batch == queries == classes
#define NL 256      // clips
#define SCALE 100.0f  // 1/TAU

typedef __attribute__((ext_vector_type(4))) unsigned int u32x4;
typedef __attribute__((ext_vector_type(4))) int i32x4;
typedef __attribute__((ext_vector_type(8))) __bf16 bfrag8;
typedef __attribute__((ext_vector_type(4))) float f32x4;

static __device__ __forceinline__ unsigned int pack2bf(float a, float b) {
  union { float f; unsigned int u; } ua, ub;
  ua.f = a; ub.f = b;
  unsigned int ra = (ua.u + 0x7FFFu + ((ua.u >> 16) & 1u)) >> 16;
  unsigned int rb = (ub.u + 0x7FFFu + ((ub.u >> 16) & 1u)) & 0xFFFF0000u;
  return ra | rb;
}

// ---------------------------------------------------------------------------
// Kernel 1 (round-11: FULL-DRAM-ROW READS).  All prior variants read 256B of
// every 1KB row (scalar 4B x 64 consecutive i) -> ~25% DRAM row utilization
// -> the invariant ~2TB/s ceiling.  Now: lane = f32x4 across i, wave = one l:
// EVERY load instr consumes a full contiguous 1KB row.  Block = 4 waves,
// 64-l tile, 4 rounds x 4 loads; per-lane 4i x 4l repack -> ds_write_b64
// ((row>>2)&7 XOR swizzle, 2-way aliasing = free), ONE barrier, then
// full-128B-line readout into [b][i][l] (proven).  Sums (pre-mask) ride
// along: LDS combine + atomicAdd into zeroed sums ws.
// ---------------------------------------------------------------------------
__global__ __launch_bounds__(256, 4) void exp_t(
    const float* __restrict__ x, const float* __restrict__ tgt,
    unsigned int* __restrict__ xsT, unsigned int* __restrict__ tsT,
    const int* __restrict__ mask,
    float* __restrict__ sumx, float* __restrict__ sumt)
{
  const int b = blockIdx.x;
  const bool is_t = (blockIdx.y != 0);
  const int lt = blockIdx.z;            // 64-l tile
  const int tid = threadIdx.x;
  const int w = tid >> 6, lane = tid & 63;
  const int lbase = lt * 64;

  const f32x4* src4 = reinterpret_cast<const f32x4*>(
      (is_t ? tgt : x) + (size_t)b * (NL * NB));
  unsigned int* dstb = (is_t ? tsT : xsT);   // u32 units, layout [b][i][l/2]

  __shared__ __align__(16) unsigned char stg[256 * 128];  // [256 i][64 l] bf16, swizzled
  __shared__ float s_ps[4][256];

  const int row0 = lane * 4;            // this lane owns rows row0..row0+3
  float psum[4] = {0.f, 0.f, 0.f, 0.f};

  #pragma unroll
  for (int r = 0; r < 4; ++r) {
    const int l0 = lbase + r * 16 + w * 4;   // 4 consecutive l's
    const int s  = r * 4 + w;                // 8B slot = (l0 - lbase) / 4
    f32x4 rv[4];
    #pragma unroll
    for (int k = 0; k < 4; ++k)
      rv[k] = src4[(size_t)(l0 + k) * 64 + lane];   // 1KB/wave/instr
    float v[4][4];
    #pragma unroll
    for (int ii = 0; ii < 4; ++ii)
      #pragma unroll
      for (int k = 0; k < 4; ++k) {
        v[ii][k] = __expf(rv[k][ii]);
        psum[ii] += v[ii][k];                // denominator: pre-mask
      }
    if (is_t) {
      #pragma unroll
      for (int ii = 0; ii < 4; ++ii) {
        i32x4 m = *reinterpret_cast<const i32x4*>(
            mask + (size_t)(row0 + ii) * NL + l0);   // L2-resident
        if (m.x <= 0) v[ii][0] = 0.f;
        if (m.y <= 0) v[ii][1] = 0.f;
        if (m.z <= 0) v[ii][2] = 0.f;
        if (m.w <= 0) v[ii][3] = 0.f;
      }
    }
    const int ch   = (s >> 1) ^ (lane & 7);  // (row>>2)&7 == lane&7 for all ii
    const int half = s & 1;
    #pragma unroll
    for (int ii = 0; ii < 4; ++ii) {
      uint2 pk;
      pk.x = pack2bf(v[ii][0], v[ii][1]);
      pk.y = pack2bf(v[ii][2], v[ii][3]);
      *reinterpret_cast<uint2*>(
          &stg[(row0 + ii) * 128 + (ch << 4) + half * 8]) = pk;
    }
  }
  #pragma unroll
  for (int ii = 0; ii < 4; ++ii) s_ps[w][row0 + ii] = psum[ii];
  __syncthreads();   // the ONLY block-wide barrier

  // readout: full 128B lines, 8 lanes per row
  const int c = tid & 7;
  #pragma unroll
  for (int k = 0; k < 8; ++k) {
    const int row = (tid >> 3) + 32 * k;
    const int chr = c ^ ((row >> 2) & 7);
    u32x4 q = *reinterpret_cast<const u32x4*>(&stg[row * 128 + (chr << 4)]);
    *reinterpret_cast<u32x4*>(
        dstb + ((size_t)b * 256 + row) * 128 + lt * 32 + c * 4) = q;
  }
  // sums: combine 4 wave-partials, one atomic per (b,i) per block (4-way)
  float tot = s_ps[0][tid] + s_ps[1][tid] + s_ps[2][tid] + s_ps[3][tid];
  atomicAdd((is_t ? sumt : sumx) + (size_t)b * 256 + tid, tot);
}

// ---------------------------------------------------------------------------
// Kernel 2 (unchanged round-9/10 LEAN gemm — ~13us measured-by-subtraction).
//   raw[j,c]   = sum_l ex[j,l] * etm[c,l]          (mask pre-applied in et)
//   logits     = SCALE * raw * irx[j] * ict[c]     (rcp's staged in LDS)
// then log-softmax over c + label-weighted diag pick -> atomicAdd.
// XCD remap (FETCH 33MB), [b][i][l] ws reads, rule #20 static acc indexing.
// ---------------------------------------------------------------------------
__global__ __launch_bounds__(256, 2) void gemm_lse(
    const unsigned short* __restrict__ xsT,
    const unsigned short* __restrict__ tsT,
    const float* __restrict__ sumx,
    const float* __restrict__ sumt,
    const int* __restrict__ label_mat,
    float* __restrict__ out)
{
  const int n  = blockIdx.x;
  const int g  = n & 7;
  const int q  = n >> 3;
  const int i  = ((q >> 2) << 3) + g;
  const int jt = q & 3;
  const int t  = threadIdx.x;
  const int w  = t >> 6;
  const int lane = t & 63;

  __shared__ __align__(16) unsigned char As[64 * 128];    // [64 j][64 l] bf16, swizzled
  __shared__ __align__(16) unsigned char Bs[256 * 128];   // [256 c][64 l] bf16, swizzled
  __shared__ float s_irx[64];    // SCALE * rcp(sumx[j][i])
  __shared__ float s_ict[256];   //         rcp(sumt[c][i])
  __shared__ float s_rmax[4][64];
  __shared__ float s_rsum[4][64];
  __shared__ float s_diag[64];

  const int srow = t >> 3;
  const int sch  = t & 7;

  s_ict[t] = __builtin_amdgcn_rcpf(sumt[(size_t)t * 256 + i]);
  if (t < 64)
    s_irx[t] = SCALE * __builtin_amdgcn_rcpf(sumx[(size_t)(jt * 64 + t) * 256 + i]);

  f32x4 acc[4][4];
  #pragma unroll
  for (int a = 0; a < 4; ++a)
    #pragma unroll
    for (int cc = 0; cc < 4; ++cc) acc[a][cc] = f32x4{0.f, 0.f, 0.f, 0.f};

  u32x4 areg[2], breg[8];

  auto load_chunk = [&](int kc) {
    const int kofs = kc * 64;
    #pragma unroll
    for (int r = 0; r < 2; ++r) {
      int row = srow + r * 32;
      areg[r] = *reinterpret_cast<const u32x4*>(
          xsT + ((size_t)(jt * 64 + row) * 256 + i) * 256 + kofs + sch * 8);
    }
    #pragma unroll
    for (int r = 0; r < 8; ++r) {
      int row = srow + r * 32;
      breg[r] = *reinterpret_cast<const u32x4*>(
          tsT + ((size_t)row * 256 + i) * 256 + kofs + sch * 8);
    }
  };
  auto store_chunk = [&]() {
    #pragma unroll
    for (int r = 0; r < 2; ++r) {
      int row = srow + r * 32;
      *reinterpret_cast<u32x4*>(&As[row * 128 + ((sch ^ (row & 7)) << 4)]) = areg[r];
    }
    #pragma unroll
    for (int r = 0; r < 8; ++r) {
      int row = srow + r * 32;
      *reinterpret_cast<u32x4*>(&Bs[row * 128 + ((sch ^ (row & 7)) << 4)]) = breg[r];
    }
  };

  load_chunk(0);
  #pragma unroll
  for (int kc = 0; kc < 4; ++kc) {
    store_chunk();
    __syncthreads();
    if (kc < 3) load_chunk(kc + 1);
    #pragma unroll
    for (int kk = 0; kk < 2; ++kk) {
      const int co = kk * 4 + (lane >> 4);
      bfrag8 af[4], bfr[4];
      #pragma unroll
      for (int jf = 0; jf < 4; ++jf) {
        int row = jf * 16 + (lane & 15);
        af[jf] = *reinterpret_cast<const bfrag8*>(
            &As[row * 128 + ((co ^ (row & 7)) << 4)]);
      }
      #pragma unroll
      for (int cf = 0; cf < 4; ++cf) {
        int row = w * 64 + cf * 16 + (lane & 15);
        bfr[cf] = *reinterpret_cast<const bfrag8*>(
            &Bs[row * 128 + ((co ^ (row & 7)) << 4)]);
      }
      #pragma unroll
      for (int jf = 0; jf < 4; ++jf)
        #pragma unroll
        for (int cf = 0; cf < 4; ++cf)
          acc[jf][cf] = __builtin_amdgcn_mfma_f32_16x16x32_bf16(
              af[jf], bfr[cf], acc[jf][cf], 0, 0, 0);
    }
    __syncthreads();
  }

  // ---- epilogue: logits = s_irx[row] * s_ict[col] * raw ----
  const int rg = (lane >> 4) << 2;

  float fr[4][4], fc[4];
  #pragma unroll
  for (int jf = 0; jf < 4; ++jf)
    #pragma unroll
    for (int reg = 0; reg < 4; ++reg)
      fr[jf][reg] = s_irx[jf * 16 + rg + reg];
  #pragma unroll
  for (int cf = 0; cf < 4; ++cf)
    fc[cf] = s_ict[w * 64 + cf * 16 + (lane & 15)];
  #pragma unroll
  for (int jf = 0; jf < 4; ++jf)
    #pragma unroll
    for (int cf = 0; cf < 4; ++cf)
      #pragma unroll
      for (int reg = 0; reg < 4; ++reg)
        acc[jf][cf][reg] *= fr[jf][reg] * fc[cf];

  #pragma unroll
  for (int jf = 0; jf < 4; ++jf) {
    #pragma unroll
    for (int reg = 0; reg < 4; ++reg) {
      float m = fmaxf(fmaxf(acc[jf][0][reg], acc[jf][1][reg]),
                      fmaxf(acc[jf][2][reg], acc[jf][3][reg]));
      #pragma unroll
      for (int off = 1; off < 16; off <<= 1) m = fmaxf(m, __shfl_xor(m, off, 64));
      if ((lane & 15) == 0) s_rmax[w][jf * 16 + rg + reg] = m;
    }
  }
  if (w == (i >> 6) && (lane & 15) == (i & 15)) {
    const int cfd = (i >> 4) & 3;
    #pragma unroll
    for (int jf = 0; jf < 4; ++jf) {
      #pragma unroll
      for (int reg = 0; reg < 4; ++reg) {
        float v = acc[jf][0][reg];
        #pragma unroll
        for (int cf = 1; cf < 4; ++cf)
          v = (cfd == cf) ? acc[jf][cf][reg] : v;
        s_diag[jf * 16 + rg + reg] = v;
      }
    }
  }
  __syncthreads();

  #pragma unroll
  for (int jf = 0; jf < 4; ++jf) {
    #pragma unroll
    for (int reg = 0; reg < 4; ++reg) {
      int row = jf * 16 + rg + reg;
      float gm = fmaxf(fmaxf(s_rmax[0][row], s_rmax[1][row]),
                       fmaxf(s_rmax[2][row], s_rmax[3][row]));
      float sE = 0.f;
      #pragma unroll
      for (int cf = 0; cf < 4; ++cf) sE += __expf(acc[jf][cf][reg] - gm);
      #pragma unroll
      for (int off = 1; off < 16; off <<= 1) sE += __shfl_xor(sE, off, 64);
      if ((lane & 15) == 0) s_rsum[w][row] = sE;
    }
  }
  __syncthreads();

  float contrib = 0.f;
  if (t < 64) {
    const int row = t;
    float gm = fmaxf(fmaxf(s_rmax[0][row], s_rmax[1][row]),
                     fmaxf(s_rmax[2][row], s_rmax[3][row]));
    float tot = s_rsum[0][row] + s_rsum[1][row] + s_rsum[2][row] + s_rsum[3][row];
    float lse = __logf(tot) + gm;
    float lbl = (float)label_mat[i * NB + jt * 64 + row];
    contrib = lbl * (s_diag[row] - lse);
  }
  #pragma unroll
  for (int off = 32; off >= 1; off >>= 1) contrib += __shfl_down(contrib, off, 64);
  if (t == 0) atomicAdd(out, contrib * (-1.0f / 256.0f));
}

extern "C" void kernel_launch(void* const* d_in, const int* in_sizes, int n_in,
                              void* d_out, int out_size, void* d_ws, size_t ws_size,
                              hipStream_t stream) {
  const float* x   = (const float*)d_in[0];
  const float* tgt = (const float*)d_in[1];
  const int* mask  = (const int*)d_in[2];
  // d_in[3] = query_labels (unused by the reference computation)
  const int* label_mat = (const int*)d_in[4];
  float* out = (float*)d_out;

  unsigned int* xsT = (unsigned int*)d_ws;                       // 32 MiB bf16 [b][i][l]
  unsigned int* tsT = xsT + (size_t)NB * NB * NL / 2;            // 32 MiB bf16 [b][i][l]
  float* sumx = (float*)(tsT + (size_t)NB * NB * NL / 2);        // 256 KiB f32 [b][i]
  float* sumt = sumx + (size_t)NB * NB;                          // 256 KiB f32 [b][i]

  hipMemsetAsync(out, 0, sizeof(float), stream);
  hipMemsetAsync(sumx, 0, 2 * (size_t)NB * NB * sizeof(float), stream);
  exp_t<<<dim3(NB, 2, 4), 256, 0, stream>>>(x, tgt, xsT, tsT, mask, sumx, sumt);
  gemm_lse<<<dim3(1024), 256, 0, stream>>>((const unsigned short*)xsT,
                                           (const unsigned short*)tsT,
                                           sumx, sumt, label_mat, out);
}

// Round 12
// 75.727 us; speedup vs baseline: 1.5315x; 1.1252x over previous
//
#include <hip/hip_runtime.h>
#include <hip/hip_bf16.h>

#define NB 256      // batch == queries == classes
#define NL 256      // clips
#define SCALE 100.0f  // 1/TAU

typedef __attribute__((ext_vector_type(4))) unsigned int u32x4;
typedef __attribute__((ext_vector_type(8))) __bf16 bfrag8;
typedef __attribute__((ext_vector_type(4))) float f32x4;

static __device__ __forceinline__ unsigned int pack2bf(float a, float b) {
  union { float f; unsigned int u; } ua, ub;
  ua.f = a; ub.f = b;
  unsigned int ra = (ua.u + 0x7FFFu + ((ua.u >> 16) & 1u)) >> 16;
  unsigned int rb = (ub.u + 0x7FFFu + ((ub.u >> 16) & 1u)) & 0xFFFF0000u;
  return ra | rb;
}

// ---------------------------------------------------------------------------
// Kernel 1 (round-12: back to the R7 structure — the variant that dropped out
// of the profile top-5 — plus denominators only).  NO MASK HERE: R9's mask
// reads (lanes spanning i = 4B-per-1KB scatter, 64 L2 lines/instr) were the
// 57->67us regression.  Mask is applied in the GEMM's B-staging instead.
//   dst[b][i][l] = bf16(exp(src[b,l,i]))        (UNMASKED)
//   sums[b][i]   = sum_l exp(src[b,l,i])        (f32, direct store, no atomics)
// LDS-staged transpose, full-128B-line stores into the block's own
// contiguous 128KB slab.
// ---------------------------------------------------------------------------
__global__ __launch_bounds__(1024, 2) void exp_t(
    const float* __restrict__ x, const float* __restrict__ tgt,
    unsigned int* __restrict__ xsT, unsigned int* __restrict__ tsT,
    float* __restrict__ sumx, float* __restrict__ sumt)
{
  const int b = blockIdx.x;
  const bool is_t = (blockIdx.y != 0);
  const int tid = threadIdx.x;
  const int i = tid & 255;
  const int h = tid >> 8;
  const float* src = (is_t ? tgt : x) + (size_t)b * (NL * NB) + i;
  unsigned int* dstb = (is_t ? tsT : xsT);  // u32 units, layout [b][i][l/2]

  __shared__ __align__(16) unsigned char stg[256 * 128];  // [i][64 l] bf16, swizzled
  __shared__ float s_sum[4][256];

  const int r0 = tid >> 3;  // writer rows r0 and r0+128
  const int c  = tid & 7;   // writer 16B chunk within 128B row-segment

  float tsum = 0.f;

  for (int lc = 0; lc < 4; ++lc) {
    float v[16];
    #pragma unroll
    for (int k = 0; k < 16; ++k)
      v[k] = __expf(src[(size_t)(lc * 64 + h * 16 + k) * NB]);
    #pragma unroll
    for (int k = 0; k < 16; ++k) tsum += v[k];
    u32x4 p0, p1;
    p0.x = pack2bf(v[0], v[1]);   p0.y = pack2bf(v[2], v[3]);
    p0.z = pack2bf(v[4], v[5]);   p0.w = pack2bf(v[6], v[7]);
    p1.x = pack2bf(v[8], v[9]);   p1.y = pack2bf(v[10], v[11]);
    p1.z = pack2bf(v[12], v[13]); p1.w = pack2bf(v[14], v[15]);
    *reinterpret_cast<u32x4*>(&stg[i * 128 + (((h * 2 + 0) ^ (i & 7)) << 4)]) = p0;
    *reinterpret_cast<u32x4*>(&stg[i * 128 + (((h * 2 + 1) ^ (i & 7)) << 4)]) = p1;
    __syncthreads();
    u32x4 q0 = *reinterpret_cast<const u32x4*>(&stg[r0 * 128 + ((c ^ (r0 & 7)) << 4)]);
    u32x4 q1 = *reinterpret_cast<const u32x4*>(&stg[(r0 + 128) * 128 + ((c ^ ((r0 + 128) & 7)) << 4)]);
    *reinterpret_cast<u32x4*>(dstb + ((size_t)b * 256 + r0) * 128 + lc * 32 + c * 4) = q0;
    *reinterpret_cast<u32x4*>(dstb + ((size_t)b * 256 + r0 + 128) * 128 + lc * 32 + c * 4) = q1;
    __syncthreads();
  }

  s_sum[h][i] = tsum;
  __syncthreads();
  if (h == 0) {
    float* so = is_t ? sumt : sumx;
    so[(size_t)b * 256 + i] = s_sum[0][i] + s_sum[1][i] + s_sum[2][i] + s_sum[3][i];
  }
}

// ---------------------------------------------------------------------------
// Kernel 2 (lean R9 gemm + mask on the B-STAGING path).
//   raw[j,c]   = sum_l ex[j,l] * (et[c,l] & m[l])   (mask ANDed during
//                ds_write staging — off the MFMA critical path; NOT the
//                round-4 per-fragment AND that caused the regression)
//   logits     = SCALE * raw * irx[j] * ict[c]      (rcp's staged in LDS)
// then log-softmax over c + label-weighted diag pick -> atomicAdd.
// XCD remap (FETCH 33MB proven), [b][i][l] ws reads (full-line groups),
// rule #20: all acc indexing compile-time.
// ---------------------------------------------------------------------------
__global__ __launch_bounds__(256, 2) void gemm_lse(
    const unsigned short* __restrict__ xsT,
    const unsigned short* __restrict__ tsT,
    const float* __restrict__ sumx,
    const float* __restrict__ sumt,
    const int* __restrict__ mask,
    const int* __restrict__ label_mat,
    float* __restrict__ out)
{
  const int n  = blockIdx.x;
  const int g  = n & 7;
  const int q  = n >> 3;
  const int i  = ((q >> 2) << 3) + g;
  const int jt = q & 3;
  const int t  = threadIdx.x;
  const int w  = t >> 6;
  const int lane = t & 63;

  __shared__ __align__(16) unsigned char As[64 * 128];    // [64 j][64 l] bf16, swizzled
  __shared__ __align__(16) unsigned char Bs[256 * 128];   // [256 c][64 l] bf16, swizzled
  __shared__ __align__(16) unsigned short s_mask[NL];     // 0xFFFF / 0 per l
  __shared__ float s_irx[64];    // SCALE * rcp(sumx[j][i])
  __shared__ float s_ict[256];   //         rcp(sumt[c][i])
  __shared__ float s_rmax[4][64];
  __shared__ float s_rsum[4][64];
  __shared__ float s_diag[64];

  const int srow = t >> 3;
  const int sch  = t & 7;

  f32x4 acc[4][4];
  #pragma unroll
  for (int a = 0; a < 4; ++a)
    #pragma unroll
    for (int cc = 0; cc < 4; ++cc) acc[a][cc] = f32x4{0.f, 0.f, 0.f, 0.f};

  u32x4 areg[2], breg[8];

  auto load_chunk = [&](int kc) {
    const int kofs = kc * 64;
    #pragma unroll
    for (int r = 0; r < 2; ++r) {
      int row = srow + r * 32;
      areg[r] = *reinterpret_cast<const u32x4*>(
          xsT + ((size_t)(jt * 64 + row) * 256 + i) * 256 + kofs + sch * 8);
    }
    #pragma unroll
    for (int r = 0; r < 8; ++r) {
      int row = srow + r * 32;
      breg[r] = *reinterpret_cast<const u32x4*>(
          tsT + ((size_t)row * 256 + i) * 256 + kofs + sch * 8);
    }
  };
  auto store_chunk = [&](int kc) {
    // mask for this thread's 8 l-positions (same for all its B rows)
    u32x4 mk = *reinterpret_cast<const u32x4*>(&s_mask[kc * 64 + sch * 8]);
    #pragma unroll
    for (int r = 0; r < 2; ++r) {
      int row = srow + r * 32;
      *reinterpret_cast<u32x4*>(&As[row * 128 + ((sch ^ (row & 7)) << 4)]) = areg[r];
    }
    #pragma unroll
    for (int r = 0; r < 8; ++r) {
      int row = srow + r * 32;
      u32x4 bm = breg[r];
      bm.x &= mk.x; bm.y &= mk.y; bm.z &= mk.z; bm.w &= mk.w;
      *reinterpret_cast<u32x4*>(&Bs[row * 128 + ((sch ^ (row & 7)) << 4)]) = bm;
    }
  };

  // issue first loads, then build s_mask/s_irx/s_ict, then barrier once
  load_chunk(0);
  s_mask[t] = (mask[i * NL + t] > 0) ? (unsigned short)0xFFFFu : (unsigned short)0u;
  s_ict[t] = __builtin_amdgcn_rcpf(sumt[(size_t)t * 256 + i]);
  if (t < 64)
    s_irx[t] = SCALE * __builtin_amdgcn_rcpf(sumx[(size_t)(jt * 64 + t) * 256 + i]);
  __syncthreads();   // s_mask ready before store_chunk reads it

  #pragma unroll
  for (int kc = 0; kc < 4; ++kc) {
    store_chunk(kc);
    __syncthreads();
    if (kc < 3) load_chunk(kc + 1);
    #pragma unroll
    for (int kk = 0; kk < 2; ++kk) {
      const int co = kk * 4 + (lane >> 4);
      bfrag8 af[4], bfr[4];
      #pragma unroll
      for (int jf = 0; jf < 4; ++jf) {
        int row = jf * 16 + (lane & 15);
        af[jf] = *reinterpret_cast<const bfrag8*>(
            &As[row * 128 + ((co ^ (row & 7)) << 4)]);
      }
      #pragma unroll
      for (int cf = 0; cf < 4; ++cf) {
        int row = w * 64 + cf * 16 + (lane & 15);
        bfr[cf] = *reinterpret_cast<const bfrag8*>(
            &Bs[row * 128 + ((co ^ (row & 7)) << 4)]);
      }
      #pragma unroll
      for (int jf = 0; jf < 4; ++jf)
        #pragma unroll
        for (int cf = 0; cf < 4; ++cf)
          acc[jf][cf] = __builtin_amdgcn_mfma_f32_16x16x32_bf16(
              af[jf], bfr[cf], acc[jf][cf], 0, 0, 0);
    }
    __syncthreads();
  }

  // ---- epilogue: logits = s_irx[row] * s_ict[col] * raw ----
  const int rg = (lane >> 4) << 2;

  float fr[4][4], fc[4];
  #pragma unroll
  for (int jf = 0; jf < 4; ++jf)
    #pragma unroll
    for (int reg = 0; reg < 4; ++reg)
      fr[jf][reg] = s_irx[jf * 16 + rg + reg];
  #pragma unroll
  for (int cf = 0; cf < 4; ++cf)
    fc[cf] = s_ict[w * 64 + cf * 16 + (lane & 15)];
  #pragma unroll
  for (int jf = 0; jf < 4; ++jf)
    #pragma unroll
    for (int cf = 0; cf < 4; ++cf)
      #pragma unroll
      for (int reg = 0; reg < 4; ++reg)
        acc[jf][cf][reg] *= fr[jf][reg] * fc[cf];

  #pragma unroll
  for (int jf = 0; jf < 4; ++jf) {
    #pragma unroll
    for (int reg = 0; reg < 4; ++reg) {
      float m = fmaxf(fmaxf(acc[jf][0][reg], acc[jf][1][reg]),
                      fmaxf(acc[jf][2][reg], acc[jf][3][reg]));
      #pragma unroll
      for (int off = 1; off < 16; off <<= 1) m = fmaxf(m, __shfl_xor(m, off, 64));
      if ((lane & 15) == 0) s_rmax[w][jf * 16 + rg + reg] = m;
    }
  }
  // diag c == i: wave i>>6, frag (i>>4)&3, lanes lane&15 == i&15 (rule #20:
  // predicated select, compile-time indices only).
  if (w == (i >> 6) && (lane & 15) == (i & 15)) {
    const int cfd = (i >> 4) & 3;
    #pragma unroll
    for (int jf = 0; jf < 4; ++jf) {
      #pragma unroll
      for (int reg = 0; reg < 4; ++reg) {
        float v = acc[jf][0][reg];
        #pragma unroll
        for (int cf = 1; cf < 4; ++cf)
          v = (cfd == cf) ? acc[jf][cf][reg] : v;
        s_diag[jf * 16 + rg + reg] = v;
      }
    }
  }
  __syncthreads();

  #pragma unroll
  for (int jf = 0; jf < 4; ++jf) {
    #pragma unroll
    for (int reg = 0; reg < 4; ++reg) {
      int row = jf * 16 + rg + reg;
      float gm = fmaxf(fmaxf(s_rmax[0][row], s_rmax[1][row]),
                       fmaxf(s_rmax[2][row], s_rmax[3][row]));
      float sE = 0.f;
      #pragma unroll
      for (int cf = 0; cf < 4; ++cf) sE += __expf(acc[jf][cf][reg] - gm);
      #pragma unroll
      for (int off = 1; off < 16; off <<= 1) sE += __shfl_xor(sE, off, 64);
      if ((lane & 15) == 0) s_rsum[w][row] = sE;
    }
  }
  __syncthreads();

  float contrib = 0.f;
  if (t < 64) {
    const int row = t;
    float gm = fmaxf(fmaxf(s_rmax[0][row], s_rmax[1][row]),
                     fmaxf(s_rmax[2][row], s_rmax[3][row]));
    float tot = s_rsum[0][row] + s_rsum[1][row] + s_rsum[2][row] + s_rsum[3][row];
    float lse = __logf(tot) + gm;
    float lbl = (float)label_mat[i * NB + jt * 64 + row];
    contrib = lbl * (s_diag[row] - lse);
  }
  #pragma unroll
  for (int off = 32; off >= 1; off >>= 1) contrib += __shfl_down(contrib, off, 64);
  if (t == 0) atomicAdd(out, contrib * (-1.0f / 256.0f));
}

extern "C" void kernel_launch(void* const* d_in, const int* in_sizes, int n_in,
                              void* d_out, int out_size, void* d_ws, size_t ws_size,
                              hipStream_t stream) {
  const float* x   = (const float*)d_in[0];
  const float* tgt = (const float*)d_in[1];
  const int* mask  = (const int*)d_in[2];
  // d_in[3] = query_labels (unused by the reference computation)
  const int* label_mat = (const int*)d_in[4];
  float* out = (float*)d_out;

  unsigned int* xsT = (unsigned int*)d_ws;                       // 32 MiB bf16 [b][i][l]
  unsigned int* tsT = xsT + (size_t)NB * NB * NL / 2;            // 32 MiB bf16 [b][i][l]
  float* sumx = (float*)(tsT + (size_t)NB * NB * NL / 2);        // 256 KiB f32 [b][i]
  float* sumt = sumx + (size_t)NB * NB;                          // 256 KiB f32 [b][i]

  hipMemsetAsync(out, 0, sizeof(float), stream);
  exp_t<<<dim3(NB, 2), 1024, 0, stream>>>(x, tgt, xsT, tsT, sumx, sumt);
  gemm_lse<<<dim3(1024), 256, 0, stream>>>((const unsigned short*)xsT,
                                           (const unsigned short*)tsT,
                                           sumx, sumt, mask, label_mat, out);
}